// Round 1
// baseline (883.231 us; speedup 1.0000x reference)
//
#include <hip/hip_runtime.h>
#include <math.h>

#define N_NODES 10000
#define K_NB    16
#define E_TOT   (N_NODES * K_NB)   // 160000
#define NO2     48                  // NL*OUT3

// One thread per edge. 16 consecutive lanes = one node (K=16 neighbors).
__global__ __launch_bounds__(256) void eq_attn_kernel(
    const float* __restrict__ b1,    // (E, 4, 2)
    const float* __restrict__ b2,    // (E, 2, 4)
    const float* __restrict__ ef,    // (E, 32)
    const float* __restrict__ f,     // (N, 8, 4)
    const int*   __restrict__ nidx,  // (E)
    const float* __restrict__ W1,    // (64, 32)
    const float* __restrict__ b1l,   // (64)
    const float* __restrict__ W2,    // (768, 64)
    const float* __restrict__ b2l,   // (768)
    const float* __restrict__ Wout,  // (16, 8)
    const float* __restrict__ bias,  // (8)
    float* __restrict__ out)         // (N, 8, 4)
{
    __shared__ float tmp2_lds[NO2][256];
    const int tid = threadIdx.x;
    const int e   = blockIdx.x * 256 + tid;   // grid sized exactly

    // ---------- load edge features into registers ----------
    float efr[32];
    {
        const float4* ef4 = reinterpret_cast<const float4*>(ef + (size_t)e * 32);
        #pragma unroll
        for (int i = 0; i < 8; ++i) {
            float4 v = ef4[i];
            efr[i * 4 + 0] = v.x; efr[i * 4 + 1] = v.y;
            efr[i * 4 + 2] = v.z; efr[i * 4 + 3] = v.w;
        }
    }

    // ---------- MLP layer 1 + exact GELU ----------
    float h[64];
    #pragma unroll
    for (int hid = 0; hid < 64; ++hid) {
        float acc = b1l[hid];
        #pragma unroll
        for (int c = 0; c < 32; ++c)
            acc = fmaf(efr[c], W1[hid * 32 + c], acc);
        h[hid] = 0.5f * acc * (1.0f + erff(acc * 0.70710678118654752f));
    }

    // ---------- tmpv = f_src (8x4) x b1f (4x2) -> 16 (j = m*2 + l) ----------
    float tmpv[16];
    {
        const int src = nidx[e];
        float fs[32];
        const float4* f4 = reinterpret_cast<const float4*>(f + (size_t)src * 32);
        #pragma unroll
        for (int i = 0; i < 8; ++i) {
            float4 v = f4[i];
            fs[i * 4 + 0] = v.x; fs[i * 4 + 1] = v.y;
            fs[i * 4 + 2] = v.z; fs[i * 4 + 3] = v.w;
        }
        float b1r[8];
        const float4* b14 = reinterpret_cast<const float4*>(b1 + (size_t)e * 8);
        float4 u0 = b14[0], u1 = b14[1];
        b1r[0] = u0.x; b1r[1] = u0.y; b1r[2] = u0.z; b1r[3] = u0.w;
        b1r[4] = u1.x; b1r[5] = u1.y; b1r[6] = u1.z; b1r[7] = u1.w;
        #pragma unroll
        for (int m = 0; m < 8; ++m) {
            float a0 = 0.f, a1 = 0.f;
            #pragma unroll
            for (int d = 0; d < 4; ++d) {
                a0 = fmaf(fs[m * 4 + d], b1r[d * 2 + 0], a0);
                a1 = fmaf(fs[m * 4 + d], b1r[d * 2 + 1], a1);
            }
            tmpv[m * 2 + 0] = a0;
            tmpv[m * 2 + 1] = a1;
        }
    }

    // ---------- layer 2 fused with rw . tmpv  -> tmp2[48] (LDS) ----------
    // tmp2[o2] = sum_j (dot64(W2[o2*16+j], h) + b2l[o2*16+j]) * tmpv[j]
    for (int o2 = 0; o2 < NO2; ++o2) {
        float acc2 = 0.f;
        #pragma unroll
        for (int j = 0; j < 16; ++j) {
            const float* wr = W2 + (size_t)(o2 * 16 + j) * 64;
            float acc = b2l[o2 * 16 + j];
            #pragma unroll
            for (int c = 0; c < 64; ++c)
                acc = fmaf(wr[c], h[c], acc);
            acc2 = fmaf(acc, tmpv[j], acc2);
        }
        tmp2_lds[o2][tid] = acc2;   // own column only, no barrier needed
    }

    // ---------- qkv = tmp2 (24x2) @ b2f (2x4) ----------
    float b2r[8];
    {
        const float4* b24 = reinterpret_cast<const float4*>(b2 + (size_t)e * 8);
        float4 u0 = b24[0], u1 = b24[1];
        b2r[0] = u0.x; b2r[1] = u0.y; b2r[2] = u0.z; b2r[3] = u0.w;
        b2r[4] = u1.x; b2r[5] = u1.y; b2r[6] = u1.z; b2r[7] = u1.w;
    }
    float q[8][4];
    #pragma unroll
    for (int o = 0; o < 8; ++o) {
        float t0 = tmp2_lds[2 * o + 0][tid];
        float t1 = tmp2_lds[2 * o + 1][tid];
        #pragma unroll
        for (int d = 0; d < 4; ++d)
            q[o][d] = fmaf(t0, b2r[d], t1 * b2r[4 + d]);
    }
    float scores[4] = {0.f, 0.f, 0.f, 0.f};
    #pragma unroll
    for (int o = 0; o < 8; ++o) {
        float t0 = tmp2_lds[16 + 2 * o + 0][tid];
        float t1 = tmp2_lds[16 + 2 * o + 1][tid];
        float sacc = 0.f;
        #pragma unroll
        for (int d = 0; d < 4; ++d) {
            float kr = fmaf(t0, b2r[d], t1 * b2r[4 + d]);
            sacc = fmaf(q[o][d], kr, sacc);
        }
        scores[o >> 1] += sacc;
    }
    float vv[8][4];
    #pragma unroll
    for (int o = 0; o < 8; ++o) {
        float t0 = tmp2_lds[32 + 2 * o + 0][tid];
        float t1 = tmp2_lds[32 + 2 * o + 1][tid];
        #pragma unroll
        for (int d = 0; d < 4; ++d)
            vv[o][d] = fmaf(t0, b2r[d], t1 * b2r[4 + d]);
    }

    // ---------- softmax over the 16 neighbor lanes ----------
    float attn[4];
    #pragma unroll
    for (int hh = 0; hh < 4; ++hh) {
        float s = scores[hh] * 0.35355339059327373f;  // HEAD_DIM^-0.5
        float mx = s;
        #pragma unroll
        for (int msk = 8; msk; msk >>= 1)
            mx = fmaxf(mx, __shfl_xor(mx, msk, 16));
        float p = __expf(s - mx);
        float ps = p;
        #pragma unroll
        for (int msk = 8; msk; msk >>= 1)
            ps += __shfl_xor(ps, msk, 16);
        attn[hh] = p / ps;
    }

    // ---------- weighted sum of V across the 16 lanes ----------
    float osum[8][4];
    #pragma unroll
    for (int m = 0; m < 8; ++m) {
        float w = attn[m >> 1];
        #pragma unroll
        for (int d = 0; d < 4; ++d) {
            float val = w * vv[m][d];
            #pragma unroll
            for (int msk = 8; msk; msk >>= 1)
                val += __shfl_xor(val, msk, 16);
            osum[m][d] = val;
        }
    }

    // ---------- out_proj (per-irrep channel mixing) + bias on l=0 slot ----------
    if ((tid & 15) == 0) {
        const int n = e >> 4;
        #pragma unroll
        for (int od = 0; od < 8; ++od) {
            #pragma unroll
            for (int d = 0; d < 4; ++d) {
                const int row = (d == 0) ? od : (8 + od);
                float acc = (d == 0) ? bias[od] : 0.f;
                #pragma unroll
                for (int m = 0; m < 8; ++m)
                    acc = fmaf(Wout[row * 8 + m], osum[m][d], acc);
                out[(size_t)n * 32 + od * 4 + d] = acc;
            }
        }
    }
}

extern "C" void kernel_launch(void* const* d_in, const int* in_sizes, int n_in,
                              void* d_out, int out_size, void* d_ws, size_t ws_size,
                              hipStream_t stream) {
    const float* b1   = (const float*)d_in[0];
    const float* b2   = (const float*)d_in[1];
    const float* ef   = (const float*)d_in[2];
    const float* f    = (const float*)d_in[3];
    const int*   nidx = (const int*)d_in[4];
    const float* W1   = (const float*)d_in[5];
    const float* b1l  = (const float*)d_in[6];
    const float* W2   = (const float*)d_in[7];
    const float* b2l  = (const float*)d_in[8];
    const float* Wout = (const float*)d_in[9];
    const float* bias = (const float*)d_in[10];
    float* out = (float*)d_out;

    hipLaunchKernelGGL(eq_attn_kernel, dim3(E_TOT / 256), dim3(256), 0, stream,
                       b1, b2, ef, f, nidx, W1, b1l, W2, b2l, Wout, bias, out);
}

// Round 4
// 225.180 us; speedup vs baseline: 3.9223x; 3.9223x over previous
//
#include <hip/hip_runtime.h>
#include <math.h>

#define E_TOT   160000
#define THREADS 128
#define NBLK    (E_TOT / THREADS)   // 1250
#define WREG    20480               // bytes per wave LDS region
#define TV_OFF  16384               // tmpv[16][64] fp32 inside region
#define T2S     52                  // tmp2 row stride (floats)

typedef __attribute__((ext_vector_type(8))) __bf16 bf16x8;
typedef __attribute__((ext_vector_type(4))) float f32x4;

static __device__ __forceinline__ unsigned short f2bf(float v) {
    unsigned int u = __float_as_uint(v);
    u += 0x7FFFu + ((u >> 16) & 1u);
    return (unsigned short)(u >> 16);
}
static __device__ __forceinline__ float bf2f(unsigned int s) {
    return __uint_as_float(s << 16);
}

// ---- pre-kernel: split W2 into bf16 hi/lo, B-fragment-coalesced layout ----
// chunk c = ((t*16 + j)*2 + kk)*64 + lane ; lane=(grp,r16)
// chunk content i=0..7 : W2[(t*16+r16)*16 + j][kk*32 + grp*8 + i]
__global__ __launch_bounds__(256) void w2_split(
    const float* __restrict__ W2, uint4* __restrict__ hi4, uint4* __restrict__ lo4)
{
    const int c    = blockIdx.x * 256 + threadIdx.x;   // 6144 chunks
    const int lane = c & 63, rest = c >> 6;
    const int kk   = rest & 1, tj = rest >> 1;
    const int j    = tj & 15,  t  = tj >> 4;
    const int grp  = lane >> 4, r16 = lane & 15;
    const float* src = W2 + (size_t)((t * 16 + r16) * 16 + j) * 64 + kk * 32 + grp * 8;
    union { uint4 u; unsigned short s[8]; } H, L;
    #pragma unroll
    for (int i = 0; i < 8; ++i) {
        float w = src[i];
        unsigned short h = f2bf(w);
        H.s[i] = h;
        L.s[i] = f2bf(w - bf2f(h));
    }
    hi4[c] = H.u;
    lo4[c] = L.u;
}

// ---- main kernel: 128 threads = 128 edges = 2 waves; all LDS wave-local ----
__global__ __launch_bounds__(THREADS) void eq_attn_kernel(
    const float* __restrict__ b1,    // (E, 4, 2)
    const float* __restrict__ b2,    // (E, 2, 4)
    const float* __restrict__ ef,    // (E, 32)
    const float* __restrict__ f,     // (N, 8, 4)
    const int*   __restrict__ nidx,  // (E)
    const float* __restrict__ W1,    // (64, 32)
    const float* __restrict__ b1l,   // (64)
    const float* __restrict__ b2l,   // (768)
    const float* __restrict__ Wout,  // (16, 8)
    const float* __restrict__ bias,  // (8)
    const uint4* __restrict__ wsh,   // W2 hi chunks (6144)
    const uint4* __restrict__ wsl,   // W2 lo chunks (6144)
    float* __restrict__ out)         // (N, 8, 4)
{
    __shared__ unsigned char smem[2 * WREG];
    const int tid  = threadIdx.x;
    const int e    = blockIdx.x * THREADS + tid;
    const int wave = tid >> 6;
    const int el   = tid & 63;
    unsigned char* wreg = smem + wave * WREG;

    // ================= phase A =================
    float efr[32];
    {
        const float4* ef4 = reinterpret_cast<const float4*>(ef + (size_t)e * 32);
        #pragma unroll
        for (int i = 0; i < 8; ++i) {
            float4 v = ef4[i];
            efr[i*4+0] = v.x; efr[i*4+1] = v.y; efr[i*4+2] = v.z; efr[i*4+3] = v.w;
        }
    }
    {   // layer 1 + exact GELU -> h ; store hi/lo bf16 (16B chunks, XOR swizzle)
        float h[64];
        #pragma unroll
        for (int hid = 0; hid < 64; ++hid) {
            float acc = b1l[hid];
            #pragma unroll
            for (int c = 0; c < 32; ++c)
                acc = fmaf(efr[c], W1[hid * 32 + c], acc);
            h[hid] = 0.5f * acc * (1.0f + erff(acc * 0.70710678118654752f));
        }
        #pragma unroll
        for (int c8 = 0; c8 < 8; ++c8) {
            union { uint4 u; unsigned short s[8]; } H, L;
            #pragma unroll
            for (int i = 0; i < 8; ++i) {
                float v = h[c8 * 8 + i];
                unsigned short hs = f2bf(v);
                H.s[i] = hs;
                L.s[i] = f2bf(v - bf2f(hs));
            }
            const int ch = c8 ^ (el & 7);
            *(uint4*)(wreg +        el * 128 + ch * 16) = H.u;
            *(uint4*)(wreg + 8192 + el * 128 + ch * 16) = L.u;
        }
    }
    float tmpv[16];
    {   // tmpv = f_src(8x4) @ b1f(4x2), fp32; regs + LDS [j][edge]
        const int src = nidx[e];
        float fs[32];
        const float4* f4 = reinterpret_cast<const float4*>(f + (size_t)src * 32);
        #pragma unroll
        for (int i = 0; i < 8; ++i) {
            float4 v = f4[i];
            fs[i*4+0] = v.x; fs[i*4+1] = v.y; fs[i*4+2] = v.z; fs[i*4+3] = v.w;
        }
        float b1r[8];
        const float4* b14 = reinterpret_cast<const float4*>(b1 + (size_t)e * 8);
        float4 u0 = b14[0], u1 = b14[1];
        b1r[0]=u0.x; b1r[1]=u0.y; b1r[2]=u0.z; b1r[3]=u0.w;
        b1r[4]=u1.x; b1r[5]=u1.y; b1r[6]=u1.z; b1r[7]=u1.w;
        float* tvp = (float*)(wreg + TV_OFF);
        #pragma unroll
        for (int m = 0; m < 8; ++m) {
            float a0 = 0.f, a1 = 0.f;
            #pragma unroll
            for (int d = 0; d < 4; ++d) {
                a0 = fmaf(fs[m*4+d], b1r[d*2+0], a0);
                a1 = fmaf(fs[m*4+d], b1r[d*2+1], a1);
            }
            tmpv[m*2+0] = a0; tmpv[m*2+1] = a1;
            tvp[(m*2+0) * 64 + el] = a0;
            tvp[(m*2+1) * 64 + el] = a1;
        }
    }

    __syncthreads();

    // ================= phase B : per-j split-bf16 MFMA =================
    const int r16 = el & 15;
    const int grp = el >> 4;

    bf16x8 Ahi[4][2], Alo[4][2];
    #pragma unroll
    for (int mt = 0; mt < 4; ++mt)
        #pragma unroll
        for (int kk = 0; kk < 2; ++kk) {
            const int row = mt * 16 + r16;
            const int ch  = (kk * 4 + grp) ^ (r16 & 7);
            Ahi[mt][kk] = *(const bf16x8*)(wreg +        row * 128 + ch * 16);
            Alo[mt][kk] = *(const bf16x8*)(wreg + 8192 + row * 128 + ch * 16);
        }

    f32x4 acc[4][3];
    #pragma unroll
    for (int mt = 0; mt < 4; ++mt)
        #pragma unroll
        for (int t = 0; t < 3; ++t)
            acc[mt][t] = (f32x4){0.f, 0.f, 0.f, 0.f};

    const float* tvp = (const float*)(wreg + TV_OFF);
    for (int j = 0; j < 16; ++j) {
        bf16x8 Bhi[3][2], Blo[3][2];
        #pragma unroll
        for (int t = 0; t < 3; ++t)
            #pragma unroll
            for (int kk = 0; kk < 2; ++kk) {
                const int chunk = ((t * 16 + j) * 2 + kk) * 64 + el;
                Bhi[t][kk] = ((const bf16x8*)wsh)[chunk];
                Blo[t][kk] = ((const bf16x8*)wsl)[chunk];
            }
        #pragma unroll
        for (int mt = 0; mt < 4; ++mt) {
            const int eb = mt * 16 + grp * 4;
            const float tv0 = tvp[j * 64 + eb + 0];
            const float tv1 = tvp[j * 64 + eb + 1];
            const float tv2 = tvp[j * 64 + eb + 2];
            const float tv3 = tvp[j * 64 + eb + 3];
            #pragma unroll
            for (int t = 0; t < 3; ++t) {
                f32x4 rw = (f32x4){0.f, 0.f, 0.f, 0.f};
                rw = __builtin_amdgcn_mfma_f32_16x16x32_bf16(Ahi[mt][0], Bhi[t][0], rw, 0, 0, 0);
                rw = __builtin_amdgcn_mfma_f32_16x16x32_bf16(Ahi[mt][1], Bhi[t][1], rw, 0, 0, 0);
                rw = __builtin_amdgcn_mfma_f32_16x16x32_bf16(Alo[mt][0], Bhi[t][0], rw, 0, 0, 0);
                rw = __builtin_amdgcn_mfma_f32_16x16x32_bf16(Alo[mt][1], Bhi[t][1], rw, 0, 0, 0);
                rw = __builtin_amdgcn_mfma_f32_16x16x32_bf16(Ahi[mt][0], Blo[t][0], rw, 0, 0, 0);
                rw = __builtin_amdgcn_mfma_f32_16x16x32_bf16(Ahi[mt][1], Blo[t][1], rw, 0, 0, 0);
                acc[mt][t].x = fmaf(tv0, rw.x, acc[mt][t].x);
                acc[mt][t].y = fmaf(tv1, rw.y, acc[mt][t].y);
                acc[mt][t].z = fmaf(tv2, rw.z, acc[mt][t].z);
                acc[mt][t].w = fmaf(tv3, rw.w, acc[mt][t].w);
            }
        }
    }

    // epilogue: tmp2 fp32 -> LDS (overlay dead h arrays)
    // D layout (m89): edge = mt*16 + grp*4 + r ; o2 = t*16 + r16
    {
        float* t2p = (float*)wreg;
        #pragma unroll
        for (int mt = 0; mt < 4; ++mt) {
            const int eb = mt * 16 + grp * 4;
            #pragma unroll
            for (int t = 0; t < 3; ++t) {
                t2p[(eb + 0) * T2S + t * 16 + r16] = acc[mt][t].x;
                t2p[(eb + 1) * T2S + t * 16 + r16] = acc[mt][t].y;
                t2p[(eb + 2) * T2S + t * 16 + r16] = acc[mt][t].z;
                t2p[(eb + 3) * T2S + t * 16 + r16] = acc[mt][t].w;
            }
        }
    }

    __syncthreads();

    // ================= phase C =================
    float t2[48];
    {
        const float* t2r = (const float*)wreg + (size_t)el * T2S;
        #pragma unroll
        for (int o2 = 0; o2 < 48; ++o2) t2[o2] = t2r[o2];
    }
    // b2_lin bias: t2[o2] += sum_j tmpv[j] * b2l[o2*16+j]  (tmpv fp32 from regs)
    #pragma unroll
    for (int o2 = 0; o2 < 48; ++o2) {
        float bt = t2[o2];
        #pragma unroll
        for (int j = 0; j < 16; ++j)
            bt = fmaf(tmpv[j], b2l[o2 * 16 + j], bt);
        t2[o2] = bt;
    }

    // qkv = tmp2(24x2) @ b2f(2x4)
    float b2r[8];
    {
        const float4* b24 = reinterpret_cast<const float4*>(b2 + (size_t)e * 8);
        float4 u0 = b24[0], u1 = b24[1];
        b2r[0]=u0.x; b2r[1]=u0.y; b2r[2]=u0.z; b2r[3]=u0.w;
        b2r[4]=u1.x; b2r[5]=u1.y; b2r[6]=u1.z; b2r[7]=u1.w;
    }
    float q[8][4];
    #pragma unroll
    for (int o = 0; o < 8; ++o) {
        float t0 = t2[2*o+0], t1 = t2[2*o+1];
        #pragma unroll
        for (int d = 0; d < 4; ++d)
            q[o][d] = fmaf(t0, b2r[d], t1 * b2r[4+d]);
    }
    float scores[4] = {0.f, 0.f, 0.f, 0.f};
    #pragma unroll
    for (int o = 0; o < 8; ++o) {
        float t0 = t2[16+2*o+0], t1 = t2[16+2*o+1];
        float sacc = 0.f;
        #pragma unroll
        for (int d = 0; d < 4; ++d) {
            float kr = fmaf(t0, b2r[d], t1 * b2r[4+d]);
            sacc = fmaf(q[o][d], kr, sacc);
        }
        scores[o >> 1] += sacc;
    }
    float vv[8][4];
    #pragma unroll
    for (int o = 0; o < 8; ++o) {
        float t0 = t2[32+2*o+0], t1 = t2[32+2*o+1];
        #pragma unroll
        for (int d = 0; d < 4; ++d)
            vv[o][d] = fmaf(t0, b2r[d], t1 * b2r[4+d]);
    }

    // softmax over the 16 neighbor lanes
    float attn[4];
    #pragma unroll
    for (int hh = 0; hh < 4; ++hh) {
        float s = scores[hh] * 0.35355339059327373f;
        float mx = s;
        #pragma unroll
        for (int msk = 8; msk; msk >>= 1)
            mx = fmaxf(mx, __shfl_xor(mx, msk, 16));
        float p = __expf(s - mx);
        float ps = p;
        #pragma unroll
        for (int msk = 8; msk; msk >>= 1)
            ps += __shfl_xor(ps, msk, 16);
        attn[hh] = p / ps;
    }

    // weighted sum of V across the 16 lanes
    float osum[8][4];
    #pragma unroll
    for (int m = 0; m < 8; ++m) {
        float w = attn[m >> 1];
        #pragma unroll
        for (int d = 0; d < 4; ++d) {
            float val = w * vv[m][d];
            #pragma unroll
            for (int msk = 8; msk; msk >>= 1)
                val += __shfl_xor(val, msk, 16);
            osum[m][d] = val;
        }
    }

    // out_proj + bias on l=0 slot
    if ((tid & 15) == 0) {
        const int n = e >> 4;
        #pragma unroll
        for (int od = 0; od < 8; ++od) {
            #pragma unroll
            for (int d = 0; d < 4; ++d) {
                const int row = (d == 0) ? od : (8 + od);
                float a = (d == 0) ? bias[od] : 0.f;
                #pragma unroll
                for (int m = 0; m < 8; ++m)
                    a = fmaf(Wout[row * 8 + m], osum[m][d], a);
                out[(size_t)n * 32 + od * 4 + d] = a;
            }
        }
    }
}

extern "C" void kernel_launch(void* const* d_in, const int* in_sizes, int n_in,
                              void* d_out, int out_size, void* d_ws, size_t ws_size,
                              hipStream_t stream) {
    const float* b1   = (const float*)d_in[0];
    const float* b2   = (const float*)d_in[1];
    const float* ef   = (const float*)d_in[2];
    const float* f    = (const float*)d_in[3];
    const int*   nidx = (const int*)d_in[4];
    const float* W1   = (const float*)d_in[5];
    const float* b1l  = (const float*)d_in[6];
    const float* W2   = (const float*)d_in[7];
    const float* b2l  = (const float*)d_in[8];
    const float* Wout = (const float*)d_in[9];
    const float* bias = (const float*)d_in[10];
    float* out = (float*)d_out;

    uint4* wsh = (uint4*)d_ws;              // 6144 * 16B = 98304
    uint4* wsl = wsh + 6144;                // another 98304

    hipLaunchKernelGGL(w2_split, dim3(24), dim3(256), 0, stream, W2, wsh, wsl);
    hipLaunchKernelGGL(eq_attn_kernel, dim3(NBLK), dim3(THREADS), 0, stream,
                       b1, b2, ef, f, nidx, W1, b1l, b2l, Wout, bias,
                       (const uint4*)wsh, (const uint4*)wsl, out);
}

// Round 5
// 193.354 us; speedup vs baseline: 4.5680x; 1.1646x over previous
//
#include <hip/hip_runtime.h>
#include <math.h>

#define E_TOT   160000
#define TPB     64
#define NBLK    (E_TOT / TPB)        // 2500 one-wave blocks
#define TV_OFF  8192                 // tv f32 [16][64] lives here during GEMM
#define T2S     52                   // tmp2 row stride (floats), 16B-aligned rows
#define SMEM_SZ 13312                // max(h-stage 8K + tv 4K, tmp2 64*52*4)

typedef __attribute__((ext_vector_type(8))) __bf16 bf16x8;
typedef __attribute__((ext_vector_type(4))) float f32x4;

static __device__ __forceinline__ unsigned short f2bf(float v) {
    unsigned int u = __float_as_uint(v);
    u += 0x7FFFu + ((u >> 16) & 1u);
    return (unsigned short)(u >> 16);
}
static __device__ __forceinline__ float bf2f(unsigned int s) {
    return __uint_as_float(s << 16);
}

// exact-enough GELU: Abramowitz-Stegun 7.1.26 erf (|err| < ~1e-6)
static __device__ __forceinline__ float gelu_exact(float a) {
    float x = a * 0.70710678118654752f;
    float s = fabsf(x);
    float t = __builtin_amdgcn_rcpf(fmaf(0.3275911f, s, 1.0f));
    float p = fmaf(1.061405429f, t, -1.453152027f);
    p = fmaf(p, t, 1.421413741f);
    p = fmaf(p, t, -0.284496736f);
    p = fmaf(p, t, 0.254829592f);
    p = p * t;
    float er = fmaf(-p, __expf(-s * s), 1.0f);   // erf(|x|)
    er = copysignf(er, x);
    return 0.5f * a * (1.0f + er);
}

// ---- pre-kernel: split W2 into bf16 hi/lo fragment chunks; bias-B chunks ----
// W2 chunk c = ((t*16 + j)*2 + kk)*64 + lane ; content i: W2[(t*16+r16)*16+j][kk*32+grp*8+i]
// bias chunk cc = t*64 + lane ; content i: grp<2 ? bf16(b2l[(t*16+r16)*16 + grp*8+i]) : 0
__global__ __launch_bounds__(256) void w_split(
    const float* __restrict__ W2, const float* __restrict__ b2l,
    uint4* __restrict__ hi4, uint4* __restrict__ lo4, uint4* __restrict__ bb4)
{
    const int c = blockIdx.x * 256 + threadIdx.x;
    if (c < 6144) {
        const int lane = c & 63, rest = c >> 6;
        const int kk   = rest & 1, tj = rest >> 1;
        const int j    = tj & 15,  t  = tj >> 4;
        const int grp  = lane >> 4, r16 = lane & 15;
        const float* src = W2 + (size_t)((t * 16 + r16) * 16 + j) * 64 + kk * 32 + grp * 8;
        union { uint4 u; unsigned short s[8]; } H, L;
        #pragma unroll
        for (int i = 0; i < 8; ++i) {
            float w = src[i];
            unsigned short h = f2bf(w);
            H.s[i] = h;
            L.s[i] = f2bf(w - bf2f(h));
        }
        hi4[c] = H.u;
        lo4[c] = L.u;
    } else if (c < 6144 + 192) {
        const int cc   = c - 6144;
        const int lane = cc & 63, t = cc >> 6;
        const int grp  = lane >> 4, r16 = lane & 15;
        union { uint4 u; unsigned short s[8]; } B;
        #pragma unroll
        for (int i = 0; i < 8; ++i)
            B.s[i] = (grp < 2) ? f2bf(b2l[(t * 16 + r16) * 16 + grp * 8 + i])
                               : (unsigned short)0;
        bb4[cc] = B.u;
    }
}

// ---- main kernel: 64 threads = 64 edges = 1 wave per block ----
__global__ __launch_bounds__(TPB) void eq_attn_kernel(
    const float* __restrict__ b1,    // (E, 4, 2)
    const float* __restrict__ b2,    // (E, 2, 4)
    const float* __restrict__ ef,    // (E, 32)
    const float* __restrict__ f,     // (N, 8, 4)
    const int*   __restrict__ nidx,  // (E)
    const float* __restrict__ W1,    // (64, 32)
    const float* __restrict__ b1l,   // (64)
    const float* __restrict__ Wout,  // (16, 8)
    const float* __restrict__ bias,  // (8)
    const uint4* __restrict__ wsh,   // W2 hi chunks (6144)
    const uint4* __restrict__ wsl,   // W2 lo chunks (6144)
    const uint4* __restrict__ bb,    // bias-B chunks (192)
    float* __restrict__ out)         // (N, 8, 4)
{
    __shared__ unsigned char smem[SMEM_SZ];
    const int tid = threadIdx.x;                 // edge-within-block, 0..63
    const int e   = blockIdx.x * TPB + tid;
    const int r16 = tid & 15;
    const int grp = tid >> 4;

    // ================= phase A =================
    float efr[32];
    {
        const float4* ef4 = reinterpret_cast<const float4*>(ef + (size_t)e * 32);
        #pragma unroll
        for (int i = 0; i < 8; ++i) {
            float4 v = ef4[i];
            efr[i*4+0] = v.x; efr[i*4+1] = v.y; efr[i*4+2] = v.z; efr[i*4+3] = v.w;
        }
    }
    // layer 1 + GELU -> split into hi/lo bf16 chunk registers
    uint4 Hc[8], Lc[8];
    {
        #pragma unroll
        for (int c8 = 0; c8 < 8; ++c8) {
            union { uint4 u; unsigned short s[8]; } H, L;
            #pragma unroll
            for (int i = 0; i < 8; ++i) {
                const int hid = c8 * 8 + i;
                float acc = b1l[hid];
                #pragma unroll
                for (int c = 0; c < 32; ++c)
                    acc = fmaf(efr[c], W1[hid * 32 + c], acc);
                float v = gelu_exact(acc);
                unsigned short hs = f2bf(v);
                H.s[i] = hs;
                L.s[i] = f2bf(v - bf2f(hs));
            }
            Hc[c8] = H.u;
            Lc[c8] = L.u;
        }
        // stage hi chunks (XOR-swizzled, conflict-free)
        #pragma unroll
        for (int c8 = 0; c8 < 8; ++c8)
            *(uint4*)(smem + tid * 128 + ((c8 ^ (tid & 7)) * 16)) = Hc[c8];
    }
    // tmpv = f_src(8x4) @ b1f(4x2): regs + LDS [j][edge] f32
    float tmpv[16];
    {
        const int src = nidx[e];
        float fs[32];
        const float4* f4 = reinterpret_cast<const float4*>(f + (size_t)src * 32);
        #pragma unroll
        for (int i = 0; i < 8; ++i) {
            float4 v = f4[i];
            fs[i*4+0] = v.x; fs[i*4+1] = v.y; fs[i*4+2] = v.z; fs[i*4+3] = v.w;
        }
        float b1r[8];
        const float4* b14 = reinterpret_cast<const float4*>(b1 + (size_t)e * 8);
        float4 u0 = b14[0], u1 = b14[1];
        b1r[0]=u0.x; b1r[1]=u0.y; b1r[2]=u0.z; b1r[3]=u0.w;
        b1r[4]=u1.x; b1r[5]=u1.y; b1r[6]=u1.z; b1r[7]=u1.w;
        float* tvp = (float*)(smem + TV_OFF);
        #pragma unroll
        for (int m = 0; m < 8; ++m) {
            float a0 = 0.f, a1 = 0.f;
            #pragma unroll
            for (int d = 0; d < 4; ++d) {
                a0 = fmaf(fs[m*4+d], b1r[d*2+0], a0);
                a1 = fmaf(fs[m*4+d], b1r[d*2+1], a1);
            }
            tmpv[m*2+0] = a0; tmpv[m*2+1] = a1;
            tvp[(m*2+0) * 64 + tid] = a0;
            tvp[(m*2+1) * 64 + tid] = a1;
        }
    }

    __syncthreads();
    // A hi fragments
    bf16x8 Ahi[4][2], Alo[4][2];
    #pragma unroll
    for (int mt = 0; mt < 4; ++mt)
        #pragma unroll
        for (int kk = 0; kk < 2; ++kk) {
            const int row = mt * 16 + r16;
            const int ch  = (kk * 4 + grp) ^ (r16 & 7);
            Ahi[mt][kk] = *(const bf16x8*)(smem + row * 128 + ch * 16);
        }
    __syncthreads();
    // restage lo into the same buffer
    #pragma unroll
    for (int c8 = 0; c8 < 8; ++c8)
        *(uint4*)(smem + tid * 128 + ((c8 ^ (tid & 7)) * 16)) = Lc[c8];
    __syncthreads();
    #pragma unroll
    for (int mt = 0; mt < 4; ++mt)
        #pragma unroll
        for (int kk = 0; kk < 2; ++kk) {
            const int row = mt * 16 + r16;
            const int ch  = (kk * 4 + grp) ^ (r16 & 7);
            Alo[mt][kk] = *(const bf16x8*)(smem + row * 128 + ch * 16);
        }
    __syncthreads();

    // ===== acc pre-init = b2l-bias GEMM: acc[mt][t] = tvA(64x32pad) @ blB =====
    f32x4 acc[4][3];
    {
        const float* tvp = (const float*)(smem + TV_OFF);
        bf16x8 tvb[4];
        #pragma unroll
        for (int mt = 0; mt < 4; ++mt) {
            union { uint4 u; unsigned short s[8]; } P;
            #pragma unroll
            for (int i = 0; i < 8; ++i) {
                float v = (grp < 2) ? tvp[(grp * 8 + i) * 64 + mt * 16 + r16] : 0.0f;
                P.s[i] = f2bf(v);
            }
            tvb[mt] = *(bf16x8*)&P.u;
        }
        bf16x8 blb[3];
        #pragma unroll
        for (int t = 0; t < 3; ++t) {
            uint4 u = bb[t * 64 + tid];
            blb[t] = *(bf16x8*)&u;
        }
        #pragma unroll
        for (int mt = 0; mt < 4; ++mt)
            #pragma unroll
            for (int t = 0; t < 3; ++t)
                acc[mt][t] = __builtin_amdgcn_mfma_f32_16x16x32_bf16(
                    tvb[mt], blb[t], (f32x4){0.f, 0.f, 0.f, 0.f}, 0, 0, 0);
    }

    // ================= phase B : per-j split-bf16 MFMA =================
    const float4* tv4 = (const float4*)(smem + TV_OFF);
    #pragma unroll 4
    for (int j = 0; j < 16; ++j) {
        bf16x8 Bhi[3][2], Blo[3][2];
        #pragma unroll
        for (int t = 0; t < 3; ++t)
            #pragma unroll
            for (int kk = 0; kk < 2; ++kk) {
                const int chunk = ((t * 16 + j) * 2 + kk) * 64 + tid;
                Bhi[t][kk] = ((const bf16x8*)wsh)[chunk];
                Blo[t][kk] = ((const bf16x8*)wsl)[chunk];
            }
        #pragma unroll
        for (int mt = 0; mt < 4; ++mt) {
            float4 tv = tv4[j * 16 + mt * 4 + grp];
            #pragma unroll
            for (int t = 0; t < 3; ++t) {
                f32x4 rw = (f32x4){0.f, 0.f, 0.f, 0.f};
                rw = __builtin_amdgcn_mfma_f32_16x16x32_bf16(Ahi[mt][0], Bhi[t][0], rw, 0, 0, 0);
                rw = __builtin_amdgcn_mfma_f32_16x16x32_bf16(Ahi[mt][1], Bhi[t][1], rw, 0, 0, 0);
                rw = __builtin_amdgcn_mfma_f32_16x16x32_bf16(Alo[mt][0], Bhi[t][0], rw, 0, 0, 0);
                rw = __builtin_amdgcn_mfma_f32_16x16x32_bf16(Alo[mt][1], Bhi[t][1], rw, 0, 0, 0);
                rw = __builtin_amdgcn_mfma_f32_16x16x32_bf16(Ahi[mt][0], Blo[t][0], rw, 0, 0, 0);
                rw = __builtin_amdgcn_mfma_f32_16x16x32_bf16(Ahi[mt][1], Blo[t][1], rw, 0, 0, 0);
                acc[mt][t].x = fmaf(tv.x, rw.x, acc[mt][t].x);
                acc[mt][t].y = fmaf(tv.y, rw.y, acc[mt][t].y);
                acc[mt][t].z = fmaf(tv.z, rw.z, acc[mt][t].z);
                acc[mt][t].w = fmaf(tv.w, rw.w, acc[mt][t].w);
            }
        }
    }

    __syncthreads();
    // epilogue: tmp2 fp32 -> LDS (overlays staging + tv regions)
    {
        float* t2p = (float*)smem;
        #pragma unroll
        for (int mt = 0; mt < 4; ++mt) {
            const int eb = mt * 16 + grp * 4;
            #pragma unroll
            for (int t = 0; t < 3; ++t) {
                t2p[(eb + 0) * T2S + t * 16 + r16] = acc[mt][t].x;
                t2p[(eb + 1) * T2S + t * 16 + r16] = acc[mt][t].y;
                t2p[(eb + 2) * T2S + t * 16 + r16] = acc[mt][t].z;
                t2p[(eb + 3) * T2S + t * 16 + r16] = acc[mt][t].w;
            }
        }
    }
    __syncthreads();

    // ================= phase C =================
    float t2[48];
    {
        const float* t2r = (const float*)smem + (size_t)tid * T2S;
        #pragma unroll
        for (int o2 = 0; o2 < 48; ++o2) t2[o2] = t2r[o2];
    }

    // qkv = tmp2(24x2) @ b2f(2x4)
    float b2r[8];
    {
        const float4* b24 = reinterpret_cast<const float4*>(b2 + (size_t)e * 8);
        float4 u0 = b24[0], u1 = b24[1];
        b2r[0]=u0.x; b2r[1]=u0.y; b2r[2]=u0.z; b2r[3]=u0.w;
        b2r[4]=u1.x; b2r[5]=u1.y; b2r[6]=u1.z; b2r[7]=u1.w;
    }
    float q[8][4];
    #pragma unroll
    for (int o = 0; o < 8; ++o) {
        float t0 = t2[2*o+0], t1 = t2[2*o+1];
        #pragma unroll
        for (int d = 0; d < 4; ++d)
            q[o][d] = fmaf(t0, b2r[d], t1 * b2r[4+d]);
    }
    float scores[4] = {0.f, 0.f, 0.f, 0.f};
    #pragma unroll
    for (int o = 0; o < 8; ++o) {
        float t0 = t2[16+2*o+0], t1 = t2[16+2*o+1];
        float sacc = 0.f;
        #pragma unroll
        for (int d = 0; d < 4; ++d) {
            float kr = fmaf(t0, b2r[d], t1 * b2r[4+d]);
            sacc = fmaf(q[o][d], kr, sacc);
        }
        scores[o >> 1] += sacc;
    }
    float vv[8][4];
    #pragma unroll
    for (int o = 0; o < 8; ++o) {
        float t0 = t2[32+2*o+0], t1 = t2[32+2*o+1];
        #pragma unroll
        for (int d = 0; d < 4; ++d)
            vv[o][d] = fmaf(t0, b2r[d], t1 * b2r[4+d]);
    }

    // softmax over the 16 neighbor lanes
    float attn[4];
    #pragma unroll
    for (int hh = 0; hh < 4; ++hh) {
        float s = scores[hh] * 0.35355339059327373f;
        float mx = s;
        #pragma unroll
        for (int msk = 8; msk; msk >>= 1)
            mx = fmaxf(mx, __shfl_xor(mx, msk, 16));
        float p = __expf(s - mx);
        float ps = p;
        #pragma unroll
        for (int msk = 8; msk; msk >>= 1)
            ps += __shfl_xor(ps, msk, 16);
        attn[hh] = p / ps;
    }

    // weighted sum of V across the 16 lanes
    float osum[8][4];
    #pragma unroll
    for (int m = 0; m < 8; ++m) {
        float w = attn[m >> 1];
        #pragma unroll
        for (int d = 0; d < 4; ++d) {
            float val = w * vv[m][d];
            #pragma unroll
            for (int msk = 8; msk; msk >>= 1)
                val += __shfl_xor(val, msk, 16);
            osum[m][d] = val;
        }
    }

    // out_proj + bias on l=0 slot
    if ((tid & 15) == 0) {
        const int n = e >> 4;
        #pragma unroll
        for (int od = 0; od < 8; ++od) {
            #pragma unroll
            for (int d = 0; d < 4; ++d) {
                const int row = (d == 0) ? od : (8 + od);
                float a = (d == 0) ? bias[od] : 0.f;
                #pragma unroll
                for (int m = 0; m < 8; ++m)
                    a = fmaf(Wout[row * 8 + m], osum[m][d], a);
                out[(size_t)n * 32 + od * 4 + d] = a;
            }
        }
    }
}

extern "C" void kernel_launch(void* const* d_in, const int* in_sizes, int n_in,
                              void* d_out, int out_size, void* d_ws, size_t ws_size,
                              hipStream_t stream) {
    const float* b1   = (const float*)d_in[0];
    const float* b2   = (const float*)d_in[1];
    const float* ef   = (const float*)d_in[2];
    const float* f    = (const float*)d_in[3];
    const int*   nidx = (const int*)d_in[4];
    const float* W1   = (const float*)d_in[5];
    const float* b1l  = (const float*)d_in[6];
    const float* W2   = (const float*)d_in[7];
    const float* b2l  = (const float*)d_in[8];
    const float* Wout = (const float*)d_in[9];
    const float* bias = (const float*)d_in[10];
    float* out = (float*)d_out;

    uint4* wsh = (uint4*)d_ws;              // 6144 chunks
    uint4* wsl = wsh + 6144;                // 6144 chunks
    uint4* bb  = wsh + 12288;               // 192 chunks

    hipLaunchKernelGGL(w_split, dim3(25), dim3(256), 0, stream, W2, b2l, wsh, wsl, bb);
    hipLaunchKernelGGL(eq_attn_kernel, dim3(NBLK), dim3(TPB), 0, stream,
                       b1, b2, ef, f, nidx, W1, b1l, Wout, bias,
                       (const uint4*)wsh, (const uint4*)wsl, (const uint4*)bb, out);
}